// Round 2
// baseline (65.184 us; speedup 1.0000x reference)
//
#include <hip/hip_runtime.h>

// out[b,s,d] = relu(x[b,s] * W[s,d] + bias[s,d])
// B=256, S=512, D=512 (fp32). Pure write-bandwidth kernel: 268 MB out.
//
// Thread assignment chosen so W/bias are loop-invariant per thread:
//   t = 0..524287; d4 = t & 127, bs0 = t >> 7 (b0 = 0..7, all s covered).
//   Each iteration advances b by 8 (bs += 4096), s and d4 fixed -> W/bias
//   loaded ONCE per thread. 32 iterations cover b = b0, b0+8, ..., b0+248.

typedef float __attribute__((ext_vector_type(4))) floatx4;

constexpr int D4      = 128;        // 512/4
constexpr int THREADS = 2048 * 256; // 524288
constexpr int ITERS   = 32;         // 16777216 float4 / 524288

__global__ void __launch_bounds__(256) od2d_kernel(
    const float*   __restrict__ x,    // [B*S]
    const floatx4* __restrict__ W4,   // [S*D4]
    const floatx4* __restrict__ b4,   // [S*D4]
    floatx4*       __restrict__ o4)   // [B*S*D4]
{
    const unsigned t   = blockIdx.x * 256 + threadIdx.x;  // 0..524287
    const unsigned d4  = t & (D4 - 1);
    const unsigned bs0 = t >> 7;                // 0..4095; s = bs0 & 511
    const unsigned s   = bs0 & 511;
    const unsigned wi  = (s << 7) + d4;

    const floatx4 w  = W4[wi];
    const floatx4 bb = b4[wi];

    unsigned i  = t;
    unsigned bs = bs0;
    #pragma unroll
    for (int k = 0; k < ITERS; ++k) {
        const float xv = x[bs];
        floatx4 r;
        r.x = fmaxf(fmaf(xv, w.x, bb.x), 0.0f);
        r.y = fmaxf(fmaf(xv, w.y, bb.y), 0.0f);
        r.z = fmaxf(fmaf(xv, w.z, bb.z), 0.0f);
        r.w = fmaxf(fmaf(xv, w.w, bb.w), 0.0f);
        __builtin_nontemporal_store(r, &o4[i]);
        i  += THREADS;
        bs += 4096;
    }
}

extern "C" void kernel_launch(void* const* d_in, const int* in_sizes, int n_in,
                              void* d_out, int out_size, void* d_ws, size_t ws_size,
                              hipStream_t stream) {
    const float*   x  = (const float*)d_in[0];
    const floatx4* W4 = (const floatx4*)d_in[1];
    const floatx4* b4 = (const floatx4*)d_in[2];
    floatx4* o4 = (floatx4*)d_out;

    od2d_kernel<<<2048, 256, 0, stream>>>(x, W4, b4, o4);
}

// Round 3
// 50.305 us; speedup vs baseline: 1.2958x; 1.2958x over previous
//
#include <hip/hip_runtime.h>

// out[b,s,d] = relu(x[b,s] * W[s,d] + bias[s,d])
// B=256, S=512, D=512 (fp32). Pure write-bandwidth kernel: 268 MB out.
//
// Thread assignment keeps W/bias loop-invariant per thread:
//   t = 0..524287; d4 = t & 127, bs0 = t >> 7.
//   Each iteration advances bs by 4096 (b += 8), s and d4 fixed -> W/bias
//   loaded ONCE per thread; 32 iterations cover b = b0, b0+8, ..., b0+248.
// Plain (cached) stores: nontemporal regressed 50 -> 65 us (round 2) —
// L2 write-back/combining is the fast path for the output stream on gfx950.

typedef float __attribute__((ext_vector_type(4))) floatx4;

constexpr int D4      = 128;        // 512/4
constexpr int THREADS = 2048 * 256; // 524288
constexpr int ITERS   = 32;         // 16777216 float4 / 524288

__global__ void __launch_bounds__(256) od2d_kernel(
    const float*   __restrict__ x,    // [B*S]
    const floatx4* __restrict__ W4,   // [S*D4]
    const floatx4* __restrict__ b4,   // [S*D4]
    floatx4*       __restrict__ o4)   // [B*S*D4]
{
    const unsigned t   = blockIdx.x * 256 + threadIdx.x;  // 0..524287
    const unsigned d4  = t & (D4 - 1);
    const unsigned bs0 = t >> 7;                // 0..4095
    const unsigned s   = bs0 & 511;
    const unsigned wi  = (s << 7) + d4;

    const floatx4 w  = W4[wi];
    const floatx4 bb = b4[wi];

    unsigned i  = t;
    unsigned bs = bs0;
    #pragma unroll
    for (int k = 0; k < ITERS; ++k) {
        const float xv = x[bs];
        floatx4 r;
        r.x = fmaxf(fmaf(xv, w.x, bb.x), 0.0f);
        r.y = fmaxf(fmaf(xv, w.y, bb.y), 0.0f);
        r.z = fmaxf(fmaf(xv, w.z, bb.z), 0.0f);
        r.w = fmaxf(fmaf(xv, w.w, bb.w), 0.0f);
        o4[i] = r;
        i  += THREADS;
        bs += 4096;
    }
}

extern "C" void kernel_launch(void* const* d_in, const int* in_sizes, int n_in,
                              void* d_out, int out_size, void* d_ws, size_t ws_size,
                              hipStream_t stream) {
    const float*   x  = (const float*)d_in[0];
    const floatx4* W4 = (const floatx4*)d_in[1];
    const floatx4* b4 = (const floatx4*)d_in[2];
    floatx4* o4 = (floatx4*)d_out;

    od2d_kernel<<<2048, 256, 0, stream>>>(x, W4, b4, o4);
}